// Round 14
// baseline (188.674 us; speedup 1.0000x reference)
//
#include <hip/hip_runtime.h>
#include <math.h>

// Damping: B=32768, N=64, H=256, OFF=2016
//   diag: x -> tanh(Wd1) -> tanh(Wd2) -> Wdo   (64 per sample)
//   off : x -> tanh(Wo1) -> tanh(Wo2) -> Woo   (2016 per sample, strict lower tri)
//   out = L (L^T x0), L diag = xd, L[i][j](j<i) = z[i(i-1)/2+j]
//
// z path: gemm_z 256x256-tile LDS-staged GEMM -> HBM in pair-interleaved
// padded-triangle groups of 32 samples -> apply (wave-local stage + 2 passes).

#define B_TOT 32768
#define NDIM  64
#define HDIM  256
#define OFFD  2016
#define QS    8192
#define GRP_UNITS 67584            // 16 pairs * 4224 bf16 units per 32-sample group
#define GRP_BYTES 135168

typedef __bf16 bf16x8 __attribute__((ext_vector_type(8)));
typedef float  f32x4  __attribute__((ext_vector_type(4)));

__device__ __forceinline__ float fast_tanh(float x) {
  float e = __expf(2.f * x);
  return 1.f - 2.f * __builtin_amdgcn_rcpf(e + 1.f);
}
__device__ __forceinline__ float lane_bcast(float v, int l) {
  return __uint_as_float(__builtin_amdgcn_readlane(__float_as_uint(v), l));
}
__device__ __forceinline__ float bf_lo(unsigned w) { return __uint_as_float(w << 16); }
__device__ __forceinline__ float bf_hi(unsigned w) { return __uint_as_float(w & 0xffff0000u); }
__device__ __forceinline__ unsigned bfbits(float f) {
  __bf16 h = (__bf16)f;
  return (unsigned)__builtin_bit_cast(unsigned short, h);
}

__device__ __forceinline__ void gload_lds16(const void* g, void* l) {
  __builtin_amdgcn_global_load_lds(
      (const __attribute__((address_space(1))) unsigned*)g,
      (__attribute__((address_space(3))) unsigned*)l, 16, 0, 0);
}

#define MFMA(A, B, C) __builtin_amdgcn_mfma_f32_16x16x32_bf16((A), (B), (C), 0, 0, 0)
#define SB0() __builtin_amdgcn_sched_barrier(0)
// XOR-swizzled 16B-granule byte offset within a row (low 3 bits of granule)
#define GOFF(g, row) (((((g) & ~7) | (((g) & 7) ^ ((row) & 7)))) << 4)

// ---------------- weight cast (f32 -> bf16) + Woob pad zero-fill ----------------
__device__ __forceinline__ void cast_range(const float* __restrict__ s,
                                           __bf16* __restrict__ d, int n) {
  int i = blockIdx.x * blockDim.x + threadIdx.x;
  const int stride = gridDim.x * blockDim.x;
  for (; i < n; i += stride) d[i] = (__bf16)s[i];
}
__global__ __launch_bounds__(256) void cast_all_kernel(
    const float* s0, __bf16* d0, int n0, const float* s1, __bf16* d1, int n1,
    const float* s2, __bf16* d2, int n2, const float* s3, __bf16* d3, int n3,
    const float* s4, __bf16* d4, int n4, const float* s5, __bf16* d5, int n5,
    __bf16* d6, int n6) {
  cast_range(s0, d0, n0); cast_range(s1, d1, n1); cast_range(s2, d2, n2);
  cast_range(s3, d3, n3); cast_range(s4, d4, n4); cast_range(s5, d5, n5);
  int i = blockIdx.x * blockDim.x + threadIdx.x;
  const int stride = gridDim.x * blockDim.x;
  for (; i < n6; i += stride) d6[i] = (__bf16)0.f;
}

__device__ __forceinline__ bf16x8 cvt8(const float* __restrict__ p) {
  const float4 u = *(const float4*)p;
  const float4 v = *(const float4*)(p + 4);
  bf16x8 r;
  r[0] = (__bf16)u.x; r[1] = (__bf16)u.y; r[2] = (__bf16)u.z; r[3] = (__bf16)u.w;
  r[4] = (__bf16)v.x; r[5] = (__bf16)v.y; r[6] = (__bf16)v.z; r[7] = (__bf16)v.w;
  return r;
}

// ---------------- shared trunk machinery: 64 samples/WG, 72KB LDS, 2 WG/CU ------
// LDS: xa 8KB | act 32KB (64 samples x 256 ch, swizzled granules) | wbuf 2x16KB
// Double-buffer discipline: stage chunk c+1 into buf (c+1)&1 while computing
// chunk c from buf c&1; __syncthreads() (drains vmcnt) certifies the stage.
#define TRK_SMEM (8192 + 32768 + 32768)

// stage one 16KB weight chunk; rows are 128B if c<2 else 512B
__device__ __forceinline__ void stage_chunk2(const char* wreg, char* wb,
                                             int c, int wave) {
  const char* base = wreg + (size_t)c * 16384;
  char* dst = wb + (c & 1) * 16384;
  const int lane = threadIdx.x & 63;
  const int s0 = wave * 64 + lane;
  const int s1 = s0 + 512;
  if (c < 2) {  // 128-byte rows (8 granules)
    const int r0 = s0 >> 3, q0 = (s0 & 7) ^ (r0 & 7);
    gload_lds16(base + r0 * 128 + (q0 << 4), dst + wave * 1024);
    const int r1 = s1 >> 3, q1 = (s1 & 7) ^ (r1 & 7);
    gload_lds16(base + r1 * 128 + (q1 << 4), dst + (wave + 8) * 1024);
  } else {      // 512-byte rows (32 granules)
    const int r0 = s0 >> 5, g0 = s0 & 31;
    const int q0 = (g0 & 24) | ((g0 & 7) ^ (r0 & 7));
    gload_lds16(base + r0 * 512 + (q0 << 4), dst + wave * 1024);
    const int r1 = s1 >> 5, g1 = s1 & 31;
    const int q1 = (g1 & 24) | ((g1 & 7) ^ (r1 & 7));
    gload_lds16(base + r1 * 512 + (q1 << 4), dst + (wave + 8) * 1024);
  }
}

// ---------------- off_trunk: x -> tanh(Wo1) -> tanh(Wo2) -> g2 ------------------
// chunks: 0-1 = Wo1 (128B rows), 2-9 = Wo2 (512B rows)
__global__ __launch_bounds__(512, 2) void off_trunk_kernel(
    const float* __restrict__ x, const __bf16* __restrict__ Wreg,
    const float* __restrict__ bo1, const float* __restrict__ bo2,
    __bf16* __restrict__ g2) {
  extern __shared__ char smem[];
  char* xa  = smem;            // 8 KB
  char* act = smem + 8192;     // 32 KB (g1)
  char* wb  = smem + 40960;    // 32 KB
  const char* Wc = (const char*)Wreg;

  const int tid = threadIdx.x;
  const int wave = tid >> 6, lane = tid & 63;
  const int lr = lane & 15, lg = lane >> 4;
  const int sb = blockIdx.x * 64;

  float bv1[2], bv2[8];
#pragma unroll
  for (int cc = 0; cc < 2; ++cc) bv1[cc] = bo1[cc * 128 + wave * 16 + lr];
#pragma unroll
  for (int cc = 0; cc < 8; ++cc) bv2[cc] = bo2[cc * 32 + (wave & 1) * 16 + lr];

  {
    const int s = tid >> 3, g = tid & 7;
    const bf16x8 v = cvt8(x + (size_t)(sb + s) * 64 + g * 8);
    *(bf16x8*)(xa + s * 128 + GOFF(g, s)) = v;
  }
  stage_chunk2(Wc, wb, 0, wave);
  __syncthreads();

  // L1o: chunks 0-1 (128 ch each); wave = n-tile
#pragma unroll
  for (int cc = 0; cc < 2; ++cc) {
    stage_chunk2(Wc, wb, cc + 1, wave);           // 1-ahead, alternate buffer
    const char* wbp = wb + (cc & 1) * 16384;
    const int brow = wave * 16 + lr;
    const bf16x8 b0 = *(const bf16x8*)(wbp + brow * 128 + GOFF(lg, brow));
    const bf16x8 b1 = *(const bf16x8*)(wbp + brow * 128 + GOFF(4 + lg, brow));
    const int ch = cc * 128 + brow;
#pragma unroll
    for (int m = 0; m < 4; ++m) {
      const int arow = m * 16 + lr;
      const bf16x8 a0 = *(const bf16x8*)(xa + arow * 128 + GOFF(lg, arow));
      const bf16x8 a1 = *(const bf16x8*)(xa + arow * 128 + GOFF(4 + lg, arow));
      f32x4 acc = {0.f, 0.f, 0.f, 0.f};
      acc = MFMA(a0, b0, acc);
      acc = MFMA(a1, b1, acc);
#pragma unroll
      for (int r = 0; r < 4; ++r) {
        const int s = m * 16 + lg * 4 + r;
        *(__bf16*)(act + s * 512 + GOFF(ch >> 3, s) + (ch & 7) * 2) =
            (__bf16)fast_tanh(acc[r] + bv1[cc]);
      }
    }
    __syncthreads();
  }

  // L2o: chunks 2-9 (32 ch each); m = wave>>1, n = wave&1
#pragma unroll
  for (int cc = 0; cc < 8; ++cc) {
    const int c = cc + 2;
    if (c + 1 < 10) stage_chunk2(Wc, wb, c + 1, wave);
    const char* wbp = wb + (c & 1) * 16384;
    const int m = wave >> 1, n = wave & 1;
    const int ch = cc * 32 + n * 16 + lr;
    const int brow = n * 16 + lr;
    const int arow = m * 16 + lr;
    f32x4 acc = {0.f, 0.f, 0.f, 0.f};
#pragma unroll
    for (int ks = 0; ks < 8; ++ks) {
      const int g = ks * 4 + lg;
      const bf16x8 a = *(const bf16x8*)(act + arow * 512 + GOFF(g, arow));
      const bf16x8 b = *(const bf16x8*)(wbp + brow * 512 + GOFF(g, brow));
      acc = MFMA(a, b, acc);
    }
#pragma unroll
    for (int r = 0; r < 4; ++r) {
      const int s = m * 16 + lg * 4 + r;
      g2[(size_t)(sb + s) * 256 + ch] = (__bf16)fast_tanh(acc[r] + bv2[cc]);
    }
    if (cc < 7) __syncthreads();
  }
}

// ---------------- diag_trunk: x -> tanh(Wd1) -> tanh(Wd2) -> Wdo -> xd ----------
// chunks: 0-1 = Wd1 (128B rows), 2-9 = Wd2, 10-11 = Wdo (512B rows)
__global__ __launch_bounds__(512, 2) void diag_trunk_kernel(
    const float* __restrict__ x, const __bf16* __restrict__ Wreg,
    const float* __restrict__ bd1, const float* __restrict__ bd2,
    const float* __restrict__ bdo, float* __restrict__ xd) {
  extern __shared__ char smem[];
  char* xa  = smem;            // 8 KB
  char* act = smem + 8192;     // 32 KB (h1, then h2)
  char* wb  = smem + 40960;    // 32 KB
  const char* Wc = (const char*)Wreg;

  const int tid = threadIdx.x;
  const int wave = tid >> 6, lane = tid & 63;
  const int lr = lane & 15, lg = lane >> 4;
  const int sb = blockIdx.x * 64;

  float bv1[2], bv2[8], bv3[2];
#pragma unroll
  for (int cc = 0; cc < 2; ++cc) bv1[cc] = bd1[cc * 128 + wave * 16 + lr];
#pragma unroll
  for (int cc = 0; cc < 8; ++cc) bv2[cc] = bd2[cc * 32 + (wave & 1) * 16 + lr];
#pragma unroll
  for (int cc = 0; cc < 2; ++cc) bv3[cc] = bdo[cc * 32 + (wave & 1) * 16 + lr];

  {
    const int s = tid >> 3, g = tid & 7;
    const bf16x8 v = cvt8(x + (size_t)(sb + s) * 64 + g * 8);
    *(bf16x8*)(xa + s * 128 + GOFF(g, s)) = v;
  }
  stage_chunk2(Wc, wb, 0, wave);
  __syncthreads();

  // L1d: chunks 0-1 -> h1 in act
#pragma unroll
  for (int cc = 0; cc < 2; ++cc) {
    stage_chunk2(Wc, wb, cc + 1, wave);
    const char* wbp = wb + (cc & 1) * 16384;
    const int brow = wave * 16 + lr;
    const bf16x8 b0 = *(const bf16x8*)(wbp + brow * 128 + GOFF(lg, brow));
    const bf16x8 b1 = *(const bf16x8*)(wbp + brow * 128 + GOFF(4 + lg, brow));
    const int ch = cc * 128 + brow;
#pragma unroll
    for (int m = 0; m < 4; ++m) {
      const int arow = m * 16 + lr;
      const bf16x8 a0 = *(const bf16x8*)(xa + arow * 128 + GOFF(lg, arow));
      const bf16x8 a1 = *(const bf16x8*)(xa + arow * 128 + GOFF(4 + lg, arow));
      f32x4 acc = {0.f, 0.f, 0.f, 0.f};
      acc = MFMA(a0, b0, acc);
      acc = MFMA(a1, b1, acc);
#pragma unroll
      for (int r = 0; r < 4; ++r) {
        const int s = m * 16 + lg * 4 + r;
        *(__bf16*)(act + s * 512 + GOFF(ch >> 3, s) + (ch & 7) * 2) =
            (__bf16)fast_tanh(acc[r] + bv1[cc]);
      }
    }
    __syncthreads();
  }

  // L2d: chunks 2-9; h2 held in registers (fully unrolled -> static indexing)
  f32x4 h2v[8];
#pragma unroll
  for (int cc = 0; cc < 8; ++cc) {
    const int c = cc + 2;
    if (c + 1 < 11) stage_chunk2(Wc, wb, c + 1, wave);  // stages up to chunk 10
    const char* wbp = wb + (c & 1) * 16384;
    const int m = wave >> 1, n = wave & 1;
    const int brow = n * 16 + lr;
    const int arow = m * 16 + lr;
    f32x4 acc = {0.f, 0.f, 0.f, 0.f};
#pragma unroll
    for (int ks = 0; ks < 8; ++ks) {
      const int g = ks * 4 + lg;
      const bf16x8 a = *(const bf16x8*)(act + arow * 512 + GOFF(g, arow));
      const bf16x8 b = *(const bf16x8*)(wbp + brow * 512 + GOFF(g, brow));
      acc = MFMA(a, b, acc);
    }
#pragma unroll
    for (int r = 0; r < 4; ++r) h2v[cc][r] = fast_tanh(acc[r] + bv2[cc]);
    __syncthreads();  // last one also certifies all h1 reads complete
  }

  // write h2 over h1; stage final chunk 11
  {
    const int m = wave >> 1, n = wave & 1;
#pragma unroll
    for (int cc = 0; cc < 8; ++cc) {
      const int ch = cc * 32 + n * 16 + lr;
#pragma unroll
      for (int r = 0; r < 4; ++r) {
        const int s = m * 16 + lg * 4 + r;
        *(__bf16*)(act + s * 512 + GOFF(ch >> 3, s) + (ch & 7) * 2) =
            (__bf16)h2v[cc][r];
      }
    }
  }
  stage_chunk2(Wc, wb, 11, wave);
  __syncthreads();

  // L3: chunks 10-11 (Wdo) -> xd f32, no tanh
#pragma unroll
  for (int cc = 0; cc < 2; ++cc) {
    const char* wbp = wb + ((10 + cc) & 1) * 16384;
    const int m = wave >> 1, n = wave & 1;
    const int ch = cc * 32 + n * 16 + lr;
    const int brow = n * 16 + lr;
    const int arow = m * 16 + lr;
    f32x4 acc = {0.f, 0.f, 0.f, 0.f};
#pragma unroll
    for (int ks = 0; ks < 8; ++ks) {
      const int g = ks * 4 + lg;
      const bf16x8 a = *(const bf16x8*)(act + arow * 512 + GOFF(g, arow));
      const bf16x8 b = *(const bf16x8*)(wbp + brow * 512 + GOFF(g, brow));
      acc = MFMA(a, b, acc);
    }
#pragma unroll
    for (int r = 0; r < 4; ++r) {
      const int s = m * 16 + lg * 4 + r;
      xd[(size_t)(sb + s) * 64 + ch] = acc[r] + bv3[cc];
    }
  }
}

// ---------------- gemm_z + u32 paired-store epilogue ----------------------------
// __launch_bounds__(512, 1): LDS (128KB) already limits to 1 WG/CU (2 waves/EU);
// min-waves=1 lifts the VGPR cap 128 -> 256 so acc[8][4] (128 VGPRs) stays
// in registers instead of spilling to scratch.
#define TILE_BYTES 32768
#define GEMM_SMEM  131072

__global__ __launch_bounds__(512, 1) void gemm_z_kernel(
    const __bf16* __restrict__ g2q, const __bf16* __restrict__ Woob,
    const float* __restrict__ boo, __bf16* __restrict__ zq) {
  extern __shared__ char gsm[];
  const int tid = threadIdx.x;
  const int wave = tid >> 6, lane = tid & 63;
  const int lr = lane & 15, lg = lane >> 4;
  const int bm = blockIdx.x & 31, bn = blockIdx.x >> 5;
  const int wr = wave >> 2, wc = wave & 3;
  const int srl = lane >> 3;
  const int sch = lane & 7;

#define STAGE(BUF, KT)                                                          \
  {                                                                             \
    _Pragma("unroll")                                                           \
    for (int j = 0; j < 4; ++j) {                                               \
      const int row = wave * 32 + j * 8 + srl;                                  \
      const int ka = (KT) * 64 + ((sch ^ (row & 7)) << 3);                      \
      gload_lds16(g2q + (size_t)(bm * 256 + row) * 256 + ka,                    \
                  gsm + (BUF) * TILE_BYTES + wave * 4096 + j * 1024);           \
      gload_lds16(Woob + (size_t)(bn * 256 + row) * 256 + ka,                   \
                  gsm + 65536 + (BUF) * TILE_BYTES + wave * 4096 + j * 1024);   \
    }                                                                           \
  }

  f32x4 acc[8][4];
#pragma unroll
  for (int i = 0; i < 8; ++i)
#pragma unroll
    for (int j = 0; j < 4; ++j) acc[i][j] = (f32x4){0.f, 0.f, 0.f, 0.f};

  STAGE(0, 0)
  __syncthreads();
#pragma unroll
  for (int kt = 0; kt < 4; ++kt) {
    if (kt < 3) STAGE((kt + 1) & 1, kt + 1)
    const __bf16* Ab = (const __bf16*)(gsm + (kt & 1) * TILE_BYTES);
    const __bf16* Bb = (const __bf16*)(gsm + 65536 + (kt & 1) * TILE_BYTES);
#pragma unroll
    for (int ks = 0; ks < 2; ++ks) {
      const int cc = ((ks * 4 + lg) ^ (lr & 7)) << 3;
      bf16x8 af[8];
#pragma unroll
      for (int fr = 0; fr < 8; ++fr)
        af[fr] = *(const bf16x8*)(Ab + (wr * 128 + fr * 16 + lr) * 64 + cc);
      bf16x8 bfr[4];
#pragma unroll
      for (int fc = 0; fc < 4; ++fc)
        bfr[fc] = *(const bf16x8*)(Bb + (wc * 64 + fc * 16 + lr) * 64 + cc);
#pragma unroll
      for (int fr = 0; fr < 8; ++fr)
#pragma unroll
        for (int fc = 0; fc < 4; ++fc)
          acc[fr][fc] = MFMA(af[fr], bfr[fc], acc[fr][fc]);
    }
    if (kt < 3) __syncthreads();
  }

  // epilogue: u32 paired stores into pair-interleaved padded triangle (+pads)
#pragma unroll
  for (int fc = 0; fc < 4; ++fc) {
    const int col = bn * 256 + wc * 64 + fc * 16 + lr;
    if (col < OFFD) {
      const float sq = sqrtf((float)(1 + 8 * col));
      const int i = (int)((1.f + sq) * 0.5f);
      const int tri = (i * (i - 1)) >> 1;
      const int r3i = i & 3;
      const int offv =
          tri + 6 * (i >> 2) + ((r3i == 2) ? 3 : (r3i == 3) ? 5 : 0) + (col - tri);
      const float bv = boo[col];
      const int pc = (4 - r3i) & 3;
      const bool lastcol = (col == tri + i - 1);
#pragma unroll
      for (int fr = 0; fr < 8; ++fr) {
#pragma unroll
        for (int h = 0; h < 2; ++h) {
          const int srow = bm * 256 + wr * 128 + fr * 16 + lg * 4 + h * 2;
          const int grp = srow >> 5, sig = srow & 31;  // sig even
          unsigned* p = (unsigned*)(zq + (size_t)grp * GRP_UNITS +
                                    (sig >> 1) * 4224 + (size_t)offv * 2);
          p[0] = bfbits(acc[fr][fc][h * 2] + bv) |
                 (bfbits(acc[fr][fc][h * 2 + 1] + bv) << 16);
          if (lastcol) {
#pragma unroll
            for (int d = 0; d < 3; ++d)
              if (d < pc) p[1 + d] = 0u;
          }
        }
      }
    }
  }
}

// ---------------- apply: wave-local stage + two triangular passes ---------------
#define APPLY_SMEM (GRP_BYTES + 8192)
__global__ __launch_bounds__(1024) void apply_kernel(
    const __bf16* __restrict__ zq, const float* __restrict__ xd,
    const float* __restrict__ x0, float* __restrict__ out, int s0base) {
  extern __shared__ char smem[];
  __bf16* ztb = (__bf16*)smem;
  float* ys2 = (float*)(smem + GRP_BYTES);

  const int tid = threadIdx.x;
  const int wave = tid >> 6, lane = tid & 63;
  const int sb = s0base + blockIdx.x * 32;
  const int s0 = wave * 2, s1 = s0 + 1;

  const float x0vA = x0[(size_t)(sb + s0) * 64 + lane];
  const float x0vB = x0[(size_t)(sb + s1) * 64 + lane];
  const float xdA = xd[(size_t)(sb + s0) * 64 + lane];
  const float xdB = xd[(size_t)(sb + s1) * 64 + lane];

  {
    const char* src = (const char*)zq + (size_t)blockIdx.x * GRP_BYTES + wave * 8448;
    char* dst = smem + wave * 8448;
#pragma unroll
    for (int j = 0; j < 8; ++j)
      gload_lds16(src + j * 1024 + lane * 16, dst + j * 1024);
    if (lane < 16) gload_lds16(src + 8192 + lane * 16, dst + 8192);
  }
  asm volatile("s_waitcnt vmcnt(0)" ::: "memory");
  SB0();

  const __bf16* zpair = ztb + wave * 4224;

  // pass 1: y_j = xd_j x0_j + sum_{k>j} z[k][j] x0_k  (one b32 = both samples)
  float yA = xdA * x0vA, yB = xdB * x0vB;
  int rs = 0;
#pragma unroll
  for (int k = 1; k < 64; ++k) {
    const unsigned w = *(const unsigned*)(zpair + (rs + lane) * 2);
    const float xkA = lane_bcast(x0vA, k);
    const float xkB = lane_bcast(x0vB, k);
    const bool mvalid = lane < k;
    yA += mvalid ? bf_lo(w) * xkA : 0.f;
    yB += mvalid ? bf_hi(w) * xkB : 0.f;
    rs += (k + 3) & ~3;
  }

  float* yp = ys2 + wave * 128;
  *(float2*)(yp + lane * 2) = make_float2(yA, yB);
  asm volatile("s_waitcnt lgkmcnt(0)" ::: "memory");
  SB0();

  // pass 2: D_i = xd_i y_i + sum_{j<i} z[i][j] y_j  (zero pads absorb masks)
  float DA = xdA * yA, DB = xdB * yB;
  float dA1 = 0.f, dB1 = 0.f;
  {
    const int r3 = lane & 3;
    const int rsi = ((lane * (lane - 1)) >> 1) + 6 * (lane >> 2) +
                    ((r3 == 2) ? 3 : (r3 == 3) ? 5 : 0);
    const int cmax = (lane + 3) >> 2;
    const __bf16* zrow = zpair + rsi * 2;
#pragma unroll 4
    for (int c = 0; c < cmax; ++c) {
      const uint4 w = *(const uint4*)(zrow + c * 8);
      const float4 u0 = *(const float4*)(yp + c * 8);
      const float4 u1 = *(const float4*)(yp + c * 8 + 4);
      DA += bf_lo(w.x) * u0.x + bf_lo(w.z) * u1.x;
      dA1 += bf_lo(w.y) * u0.z + bf_lo(w.w) * u1.z;
      DB += bf_hi(w.x) * u0.y + bf_hi(w.z) * u1.y;
      dB1 += bf_hi(w.y) * u0.w + bf_hi(w.w) * u1.w;
    }
  }
  out[(size_t)(sb + s0) * 64 + lane] = DA + dA1;
  out[(size_t)(sb + s1) * 64 + lane] = DB + dB1;
}

// ---------------- launch ----------------
extern "C" void kernel_launch(void* const* d_in, const int* in_sizes, int n_in,
                              void* d_out, int out_size, void* d_ws, size_t ws_size,
                              hipStream_t stream) {
  const float* x   = (const float*)d_in[0];
  const float* Wd1 = (const float*)d_in[1];
  const float* bd1 = (const float*)d_in[2];
  const float* Wd2 = (const float*)d_in[3];
  const float* bd2 = (const float*)d_in[4];
  const float* Wdo = (const float*)d_in[5];
  const float* bdo = (const float*)d_in[6];
  const float* Wo1 = (const float*)d_in[7];
  const float* bo1 = (const float*)d_in[8];
  const float* Wo2 = (const float*)d_in[9];
  const float* bo2 = (const float*)d_in[10];
  const float* Woo = (const float*)d_in[11];
  const float* boo = (const float*)d_in[12];
  float* out = (float*)d_out;

  char* ws = (char*)d_ws;
  // Wcat (bf16 elems): Wo1@0 | Wo2@16384 | Wd1@81920 | Wd2@98304 | Wdo@163840
  __bf16* Wcat = (__bf16*)(ws + 0);          //   360448 B
  __bf16* Woob = (__bf16*)(ws + 360448);     //  1048576 B (zero-padded rows)
  __bf16* g2   = (__bf16*)(ws + 1409024);    // 16777216 B
  float*  xdp  = (float*)(ws + 18186240);    //  8388608 B
  __bf16* zq   = (__bf16*)(ws + 26574848);   // 34603008 B (one quarter)

  cast_all_kernel<<<512, 256, 0, stream>>>(
      Wo1, Wcat, HDIM * NDIM,
      Wo2, Wcat + 16384, HDIM * HDIM,
      Wd1, Wcat + 81920, HDIM * NDIM,
      Wd2, Wcat + 98304, HDIM * HDIM,
      Wdo, Wcat + 163840, NDIM * HDIM,
      Woo, Woob, OFFD * HDIM,
      Woob + OFFD * HDIM, 32 * HDIM);

  hipFuncSetAttribute((const void*)off_trunk_kernel,
                      hipFuncAttributeMaxDynamicSharedMemorySize, TRK_SMEM);
  hipFuncSetAttribute((const void*)diag_trunk_kernel,
                      hipFuncAttributeMaxDynamicSharedMemorySize, TRK_SMEM);
  off_trunk_kernel<<<B_TOT / 64, 512, TRK_SMEM, stream>>>(
      x, Wcat, bo1, bo2, g2);
  diag_trunk_kernel<<<B_TOT / 64, 512, TRK_SMEM, stream>>>(
      x, Wcat + 81920, bd1, bd2, bdo, xdp);

  hipFuncSetAttribute((const void*)gemm_z_kernel,
                      hipFuncAttributeMaxDynamicSharedMemorySize, GEMM_SMEM);
  hipFuncSetAttribute((const void*)apply_kernel,
                      hipFuncAttributeMaxDynamicSharedMemorySize, APPLY_SMEM);
  for (int q = 0; q < 4; ++q) {
    gemm_z_kernel<<<(QS / 256) * 8, 512, GEMM_SMEM, stream>>>(
        g2 + (size_t)q * QS * HDIM, Woob, boo, zq);
    apply_kernel<<<QS / 32, 1024, APPLY_SMEM, stream>>>(zq, xdp, x, out, q * QS);
  }
}

// Round 15
// 164.531 us; speedup vs baseline: 1.1467x; 1.1467x over previous
//
#include <hip/hip_runtime.h>
#include <math.h>

// Damping: B=32768, N=64, H=256, OFF=2016
//   diag: x -> tanh(Wd1) -> tanh(Wd2) -> Wdo   (64 per sample)
//   off : x -> tanh(Wo1) -> tanh(Wo2) -> Woo   (2016 per sample, strict lower tri)
//   out = L (L^T x0), L diag = xd, L[i][j](j<i) = z[i(i-1)/2+j]
//
// z path: gemm_z 256x256-tile LDS-staged GEMM -> HBM/L3 in pair-interleaved
// padded-triangle groups of 32 samples -> apply (wave-local stage + 2 passes).
// z is processed in 1/2/4 slices depending on ws_size (single-shot if it fits).

#define B_TOT 32768
#define NDIM  64
#define HDIM  256
#define OFFD  2016
#define GRP_UNITS 67584            // 16 pairs * 4224 bf16 units per 32-sample group
#define GRP_BYTES 135168

typedef __bf16 bf16x8 __attribute__((ext_vector_type(8)));
typedef float  f32x4  __attribute__((ext_vector_type(4)));

__device__ __forceinline__ float fast_tanh(float x) {
  float e = __expf(2.f * x);
  return 1.f - 2.f * __builtin_amdgcn_rcpf(e + 1.f);
}
__device__ __forceinline__ float lane_bcast(float v, int l) {
  return __uint_as_float(__builtin_amdgcn_readlane(__float_as_uint(v), l));
}
__device__ __forceinline__ float bf_lo(unsigned w) { return __uint_as_float(w << 16); }
__device__ __forceinline__ float bf_hi(unsigned w) { return __uint_as_float(w & 0xffff0000u); }
__device__ __forceinline__ unsigned bfbits(float f) {
  __bf16 h = (__bf16)f;
  return (unsigned)__builtin_bit_cast(unsigned short, h);
}

__device__ __forceinline__ void gload_lds16(const void* g, void* l) {
  __builtin_amdgcn_global_load_lds(
      (const __attribute__((address_space(1))) unsigned*)g,
      (__attribute__((address_space(3))) unsigned*)l, 16, 0, 0);
}

#define MFMA(A, B, C) __builtin_amdgcn_mfma_f32_16x16x32_bf16((A), (B), (C), 0, 0, 0)
#define SB0() __builtin_amdgcn_sched_barrier(0)
// XOR-swizzled 16B-granule byte offset within a row (low 3 bits of granule)
#define GOFF(g, row) (((((g) & ~7) | (((g) & 7) ^ ((row) & 7)))) << 4)

// ---------------- weight cast (f32 -> bf16) + Woob pad zero-fill ----------------
__device__ __forceinline__ void cast_range(const float* __restrict__ s,
                                           __bf16* __restrict__ d, int n) {
  int i = blockIdx.x * blockDim.x + threadIdx.x;
  const int stride = gridDim.x * blockDim.x;
  for (; i < n; i += stride) d[i] = (__bf16)s[i];
}
__global__ __launch_bounds__(256) void cast_all_kernel(
    const float* s0, __bf16* d0, int n0, const float* s1, __bf16* d1, int n1,
    const float* s2, __bf16* d2, int n2, const float* s3, __bf16* d3, int n3,
    const float* s4, __bf16* d4, int n4, const float* s5, __bf16* d5, int n5,
    __bf16* d6, int n6) {
  cast_range(s0, d0, n0); cast_range(s1, d1, n1); cast_range(s2, d2, n2);
  cast_range(s3, d3, n3); cast_range(s4, d4, n4); cast_range(s5, d5, n5);
  int i = blockIdx.x * blockDim.x + threadIdx.x;
  const int stride = gridDim.x * blockDim.x;
  for (; i < n6; i += stride) d6[i] = (__bf16)0.f;
}

__device__ __forceinline__ bf16x8 cvt8(const float* __restrict__ p) {
  const float4 u = *(const float4*)p;
  const float4 v = *(const float4*)(p + 4);
  bf16x8 r;
  r[0] = (__bf16)u.x; r[1] = (__bf16)u.y; r[2] = (__bf16)u.z; r[3] = (__bf16)u.w;
  r[4] = (__bf16)v.x; r[5] = (__bf16)v.y; r[6] = (__bf16)v.z; r[7] = (__bf16)v.w;
  return r;
}

// ---------------- shared trunk machinery: 64 samples/WG, 72KB LDS, 2 WG/CU ------
#define TRK_SMEM (8192 + 32768 + 32768)

// stage one 16KB weight chunk; rows are 128B if c<2 else 512B
__device__ __forceinline__ void stage_chunk2(const char* wreg, char* wb,
                                             int c, int wave) {
  const char* base = wreg + (size_t)c * 16384;
  char* dst = wb + (c & 1) * 16384;
  const int lane = threadIdx.x & 63;
  const int s0 = wave * 64 + lane;
  const int s1 = s0 + 512;
  if (c < 2) {  // 128-byte rows (8 granules)
    const int r0 = s0 >> 3, q0 = (s0 & 7) ^ (r0 & 7);
    gload_lds16(base + r0 * 128 + (q0 << 4), dst + wave * 1024);
    const int r1 = s1 >> 3, q1 = (s1 & 7) ^ (r1 & 7);
    gload_lds16(base + r1 * 128 + (q1 << 4), dst + (wave + 8) * 1024);
  } else {      // 512-byte rows (32 granules)
    const int r0 = s0 >> 5, g0 = s0 & 31;
    const int q0 = (g0 & 24) | ((g0 & 7) ^ (r0 & 7));
    gload_lds16(base + r0 * 512 + (q0 << 4), dst + wave * 1024);
    const int r1 = s1 >> 5, g1 = s1 & 31;
    const int q1 = (g1 & 24) | ((g1 & 7) ^ (r1 & 7));
    gload_lds16(base + r1 * 512 + (q1 << 4), dst + (wave + 8) * 1024);
  }
}

// ---------------- off_trunk: x -> tanh(Wo1) -> tanh(Wo2) -> g2 ------------------
__global__ __launch_bounds__(512, 2) void off_trunk_kernel(
    const float* __restrict__ x, const __bf16* __restrict__ Wreg,
    const float* __restrict__ bo1, const float* __restrict__ bo2,
    __bf16* __restrict__ g2) {
  extern __shared__ char smem[];
  char* xa  = smem;            // 8 KB
  char* act = smem + 8192;     // 32 KB (g1)
  char* wb  = smem + 40960;    // 32 KB
  const char* Wc = (const char*)Wreg;

  const int tid = threadIdx.x;
  const int wave = tid >> 6, lane = tid & 63;
  const int lr = lane & 15, lg = lane >> 4;
  const int sb = blockIdx.x * 64;

  float bv1[2], bv2[8];
#pragma unroll
  for (int cc = 0; cc < 2; ++cc) bv1[cc] = bo1[cc * 128 + wave * 16 + lr];
#pragma unroll
  for (int cc = 0; cc < 8; ++cc) bv2[cc] = bo2[cc * 32 + (wave & 1) * 16 + lr];

  {
    const int s = tid >> 3, g = tid & 7;
    const bf16x8 v = cvt8(x + (size_t)(sb + s) * 64 + g * 8);
    *(bf16x8*)(xa + s * 128 + GOFF(g, s)) = v;
  }
  stage_chunk2(Wc, wb, 0, wave);
  __syncthreads();

#pragma unroll
  for (int cc = 0; cc < 2; ++cc) {
    stage_chunk2(Wc, wb, cc + 1, wave);
    const char* wbp = wb + (cc & 1) * 16384;
    const int brow = wave * 16 + lr;
    const bf16x8 b0 = *(const bf16x8*)(wbp + brow * 128 + GOFF(lg, brow));
    const bf16x8 b1 = *(const bf16x8*)(wbp + brow * 128 + GOFF(4 + lg, brow));
    const int ch = cc * 128 + brow;
#pragma unroll
    for (int m = 0; m < 4; ++m) {
      const int arow = m * 16 + lr;
      const bf16x8 a0 = *(const bf16x8*)(xa + arow * 128 + GOFF(lg, arow));
      const bf16x8 a1 = *(const bf16x8*)(xa + arow * 128 + GOFF(4 + lg, arow));
      f32x4 acc = {0.f, 0.f, 0.f, 0.f};
      acc = MFMA(a0, b0, acc);
      acc = MFMA(a1, b1, acc);
#pragma unroll
      for (int r = 0; r < 4; ++r) {
        const int s = m * 16 + lg * 4 + r;
        *(__bf16*)(act + s * 512 + GOFF(ch >> 3, s) + (ch & 7) * 2) =
            (__bf16)fast_tanh(acc[r] + bv1[cc]);
      }
    }
    __syncthreads();
  }

#pragma unroll
  for (int cc = 0; cc < 8; ++cc) {
    const int c = cc + 2;
    if (c + 1 < 10) stage_chunk2(Wc, wb, c + 1, wave);
    const char* wbp = wb + (c & 1) * 16384;
    const int m = wave >> 1, n = wave & 1;
    const int ch = cc * 32 + n * 16 + lr;
    const int brow = n * 16 + lr;
    const int arow = m * 16 + lr;
    f32x4 acc = {0.f, 0.f, 0.f, 0.f};
#pragma unroll
    for (int ks = 0; ks < 8; ++ks) {
      const int g = ks * 4 + lg;
      const bf16x8 a = *(const bf16x8*)(act + arow * 512 + GOFF(g, arow));
      const bf16x8 b = *(const bf16x8*)(wbp + brow * 512 + GOFF(g, brow));
      acc = MFMA(a, b, acc);
    }
#pragma unroll
    for (int r = 0; r < 4; ++r) {
      const int s = m * 16 + lg * 4 + r;
      g2[(size_t)(sb + s) * 256 + ch] = (__bf16)fast_tanh(acc[r] + bv2[cc]);
    }
    if (cc < 7) __syncthreads();
  }
}

// ---------------- diag_trunk: x -> tanh(Wd1) -> tanh(Wd2) -> Wdo -> xd ----------
__global__ __launch_bounds__(512, 2) void diag_trunk_kernel(
    const float* __restrict__ x, const __bf16* __restrict__ Wreg,
    const float* __restrict__ bd1, const float* __restrict__ bd2,
    const float* __restrict__ bdo, float* __restrict__ xd) {
  extern __shared__ char smem[];
  char* xa  = smem;            // 8 KB
  char* act = smem + 8192;     // 32 KB (h1, then h2)
  char* wb  = smem + 40960;    // 32 KB
  const char* Wc = (const char*)Wreg;

  const int tid = threadIdx.x;
  const int wave = tid >> 6, lane = tid & 63;
  const int lr = lane & 15, lg = lane >> 4;
  const int sb = blockIdx.x * 64;

  float bv1[2], bv2[8], bv3[2];
#pragma unroll
  for (int cc = 0; cc < 2; ++cc) bv1[cc] = bd1[cc * 128 + wave * 16 + lr];
#pragma unroll
  for (int cc = 0; cc < 8; ++cc) bv2[cc] = bd2[cc * 32 + (wave & 1) * 16 + lr];
#pragma unroll
  for (int cc = 0; cc < 2; ++cc) bv3[cc] = bdo[cc * 32 + (wave & 1) * 16 + lr];

  {
    const int s = tid >> 3, g = tid & 7;
    const bf16x8 v = cvt8(x + (size_t)(sb + s) * 64 + g * 8);
    *(bf16x8*)(xa + s * 128 + GOFF(g, s)) = v;
  }
  stage_chunk2(Wc, wb, 0, wave);
  __syncthreads();

#pragma unroll
  for (int cc = 0; cc < 2; ++cc) {
    stage_chunk2(Wc, wb, cc + 1, wave);
    const char* wbp = wb + (cc & 1) * 16384;
    const int brow = wave * 16 + lr;
    const bf16x8 b0 = *(const bf16x8*)(wbp + brow * 128 + GOFF(lg, brow));
    const bf16x8 b1 = *(const bf16x8*)(wbp + brow * 128 + GOFF(4 + lg, brow));
    const int ch = cc * 128 + brow;
#pragma unroll
    for (int m = 0; m < 4; ++m) {
      const int arow = m * 16 + lr;
      const bf16x8 a0 = *(const bf16x8*)(xa + arow * 128 + GOFF(lg, arow));
      const bf16x8 a1 = *(const bf16x8*)(xa + arow * 128 + GOFF(4 + lg, arow));
      f32x4 acc = {0.f, 0.f, 0.f, 0.f};
      acc = MFMA(a0, b0, acc);
      acc = MFMA(a1, b1, acc);
#pragma unroll
      for (int r = 0; r < 4; ++r) {
        const int s = m * 16 + lg * 4 + r;
        *(__bf16*)(act + s * 512 + GOFF(ch >> 3, s) + (ch & 7) * 2) =
            (__bf16)fast_tanh(acc[r] + bv1[cc]);
      }
    }
    __syncthreads();
  }

  f32x4 h2v[8];
#pragma unroll
  for (int cc = 0; cc < 8; ++cc) {
    const int c = cc + 2;
    if (c + 1 < 11) stage_chunk2(Wc, wb, c + 1, wave);
    const char* wbp = wb + (c & 1) * 16384;
    const int m = wave >> 1, n = wave & 1;
    const int brow = n * 16 + lr;
    const int arow = m * 16 + lr;
    f32x4 acc = {0.f, 0.f, 0.f, 0.f};
#pragma unroll
    for (int ks = 0; ks < 8; ++ks) {
      const int g = ks * 4 + lg;
      const bf16x8 a = *(const bf16x8*)(act + arow * 512 + GOFF(g, arow));
      const bf16x8 b = *(const bf16x8*)(wbp + brow * 512 + GOFF(g, brow));
      acc = MFMA(a, b, acc);
    }
#pragma unroll
    for (int r = 0; r < 4; ++r) h2v[cc][r] = fast_tanh(acc[r] + bv2[cc]);
    __syncthreads();
  }

  {
    const int m = wave >> 1, n = wave & 1;
#pragma unroll
    for (int cc = 0; cc < 8; ++cc) {
      const int ch = cc * 32 + n * 16 + lr;
#pragma unroll
      for (int r = 0; r < 4; ++r) {
        const int s = m * 16 + lg * 4 + r;
        *(__bf16*)(act + s * 512 + GOFF(ch >> 3, s) + (ch & 7) * 2) =
            (__bf16)h2v[cc][r];
      }
    }
  }
  stage_chunk2(Wc, wb, 11, wave);
  __syncthreads();

#pragma unroll
  for (int cc = 0; cc < 2; ++cc) {
    const char* wbp = wb + ((10 + cc) & 1) * 16384;
    const int m = wave >> 1, n = wave & 1;
    const int ch = cc * 32 + n * 16 + lr;
    const int brow = n * 16 + lr;
    const int arow = m * 16 + lr;
    f32x4 acc = {0.f, 0.f, 0.f, 0.f};
#pragma unroll
    for (int ks = 0; ks < 8; ++ks) {
      const int g = ks * 4 + lg;
      const bf16x8 a = *(const bf16x8*)(act + arow * 512 + GOFF(g, arow));
      const bf16x8 b = *(const bf16x8*)(wbp + brow * 512 + GOFF(g, brow));
      acc = MFMA(a, b, acc);
    }
#pragma unroll
    for (int r = 0; r < 4; ++r) {
      const int s = m * 16 + lg * 4 + r;
      xd[(size_t)(sb + s) * 64 + ch] = acc[r] + bv3[cc];
    }
  }
}

// ---------------- gemm_z: z[QSs x 2016] = G @ Woo^T + boo -----------------------
// 256x256 tiles, BK=64, 8 waves; XCD-pinned bn (swz), u32 paired-store epilogue.
#define TILE_BYTES 32768
#define GEMM_SMEM  131072

__global__ __launch_bounds__(512, 1) void gemm_z_kernel(
    const __bf16* __restrict__ g2q, const __bf16* __restrict__ Woob,
    const float* __restrict__ boo, __bf16* __restrict__ zq, int lbm) {
  extern __shared__ char gsm[];
  const int tid = threadIdx.x;
  const int wave = tid >> 6, lane = tid & 63;
  const int lr = lane & 15, lg = lane >> 4;
  // XCD swizzle (nwg = 8*nbm, nwg%8==0): XCD i owns bn=i -> Woo panel L2-resident
  const int nbm = 1 << lbm;
  const int swz = (blockIdx.x & 7) * nbm + (blockIdx.x >> 3);
  const int bm = swz & (nbm - 1), bn = swz >> lbm;
  const int wr = wave >> 2, wc = wave & 3;
  const int srl = lane >> 3;
  const int sch = lane & 7;

#define STAGE(BUF, KT)                                                          \
  {                                                                             \
    _Pragma("unroll")                                                           \
    for (int j = 0; j < 4; ++j) {                                               \
      const int row = wave * 32 + j * 8 + srl;                                  \
      const int ka = (KT) * 64 + ((sch ^ (row & 7)) << 3);                      \
      gload_lds16(g2q + (size_t)(bm * 256 + row) * 256 + ka,                    \
                  gsm + (BUF) * TILE_BYTES + wave * 4096 + j * 1024);           \
      gload_lds16(Woob + (size_t)(bn * 256 + row) * 256 + ka,                   \
                  gsm + 65536 + (BUF) * TILE_BYTES + wave * 4096 + j * 1024);   \
    }                                                                           \
  }

  f32x4 acc[8][4];
#pragma unroll
  for (int i = 0; i < 8; ++i)
#pragma unroll
    for (int j = 0; j < 4; ++j) acc[i][j] = (f32x4){0.f, 0.f, 0.f, 0.f};

  STAGE(0, 0)
  __syncthreads();
#pragma unroll
  for (int kt = 0; kt < 4; ++kt) {
    if (kt < 3) STAGE((kt + 1) & 1, kt + 1)
    const __bf16* Ab = (const __bf16*)(gsm + (kt & 1) * TILE_BYTES);
    const __bf16* Bb = (const __bf16*)(gsm + 65536 + (kt & 1) * TILE_BYTES);
#pragma unroll
    for (int ks = 0; ks < 2; ++ks) {
      const int cc = ((ks * 4 + lg) ^ (lr & 7)) << 3;
      bf16x8 af[8];
#pragma unroll
      for (int fr = 0; fr < 8; ++fr)
        af[fr] = *(const bf16x8*)(Ab + (wr * 128 + fr * 16 + lr) * 64 + cc);
      bf16x8 bfr[4];
#pragma unroll
      for (int fc = 0; fc < 4; ++fc)
        bfr[fc] = *(const bf16x8*)(Bb + (wc * 64 + fc * 16 + lr) * 64 + cc);
#pragma unroll
      for (int fr = 0; fr < 8; ++fr)
#pragma unroll
        for (int fc = 0; fc < 4; ++fc)
          acc[fr][fc] = MFMA(af[fr], bfr[fc], acc[fr][fc]);
    }
    if (kt < 3) __syncthreads();
  }

  // epilogue: u32 paired stores into pair-interleaved padded triangle (+pads)
#pragma unroll
  for (int fc = 0; fc < 4; ++fc) {
    const int col = bn * 256 + wc * 64 + fc * 16 + lr;
    if (col < OFFD) {
      const float sq = sqrtf((float)(1 + 8 * col));
      const int i = (int)((1.f + sq) * 0.5f);
      const int tri = (i * (i - 1)) >> 1;
      const int r3i = i & 3;
      const int offv =
          tri + 6 * (i >> 2) + ((r3i == 2) ? 3 : (r3i == 3) ? 5 : 0) + (col - tri);
      const float bv = boo[col];
      const int pc = (4 - r3i) & 3;
      const bool lastcol = (col == tri + i - 1);
#pragma unroll
      for (int fr = 0; fr < 8; ++fr) {
#pragma unroll
        for (int h = 0; h < 2; ++h) {
          const int srow = bm * 256 + wr * 128 + fr * 16 + lg * 4 + h * 2;
          const int grp = srow >> 5, sig = srow & 31;  // sig even
          unsigned* p = (unsigned*)(zq + (size_t)grp * GRP_UNITS +
                                    (sig >> 1) * 4224 + (size_t)offv * 2);
          p[0] = bfbits(acc[fr][fc][h * 2] + bv) |
                 (bfbits(acc[fr][fc][h * 2 + 1] + bv) << 16);
          if (lastcol) {
#pragma unroll
            for (int d = 0; d < 3; ++d)
              if (d < pc) p[1 + d] = 0u;
          }
        }
      }
    }
  }
}

// ---------------- apply: 512 thr, 16 samples (half group) -> 2 WG/CU ------------
#define APPLY_SMEM (8 * 8448 + 4096)
__global__ __launch_bounds__(512, 2) void apply_kernel(
    const __bf16* __restrict__ zq, const float* __restrict__ xd,
    const float* __restrict__ x0, float* __restrict__ out, int s0base) {
  extern __shared__ char smem[];
  __bf16* ztb = (__bf16*)smem;                 // 8 pairs x 4224 units
  float* ys2 = (float*)(smem + 8 * 8448);      // [8][128]

  const int tid = threadIdx.x;
  const int wave = tid >> 6, lane = tid & 63;
  const int blk = blockIdx.x;
  const int sb = s0base + blk * 16;            // global sample base of this WG
  const int s0 = wave * 2, s1 = s0 + 1;        // local samples within the 16

  const float x0vA = x0[(size_t)(sb + s0) * 64 + lane];
  const float x0vB = x0[(size_t)(sb + s1) * 64 + lane];
  const float xdA = xd[(size_t)(sb + s0) * 64 + lane];
  const float xdB = xd[(size_t)(sb + s1) * 64 + lane];

  // stage this wave's pair slice (8448 B): group blk>>1, half blk&1, pair wave
  {
    const char* src = (const char*)zq + (size_t)(blk >> 1) * GRP_BYTES +
                      ((blk & 1) * 8 + wave) * 8448;
    char* dst = smem + wave * 8448;
#pragma unroll
    for (int j = 0; j < 8; ++j)
      gload_lds16(src + j * 1024 + lane * 16, dst + j * 1024);
    if (lane < 16) gload_lds16(src + 8192 + lane * 16, dst + 8192);
  }
  asm volatile("s_waitcnt vmcnt(0)" ::: "memory");
  SB0();

  const __bf16* zpair = ztb + wave * 4224;

  // pass 1: y_j = xd_j x0_j + sum_{k>j} z[k][j] x0_k  (one b32 = both samples)
  float yA = xdA * x0vA, yB = xdB * x0vB;
  int rs = 0;
#pragma unroll
  for (int k = 1; k < 64; ++k) {
    const unsigned w = *(const unsigned*)(zpair + (rs + lane) * 2);
    const float xkA = lane_bcast(x0vA, k);
    const float xkB = lane_bcast(x0vB, k);
    const bool mvalid = lane < k;
    yA += mvalid ? bf_lo(w) * xkA : 0.f;
    yB += mvalid ? bf_hi(w) * xkB : 0.f;
    rs += (k + 3) & ~3;
  }

  float* yp = ys2 + wave * 128;
  *(float2*)(yp + lane * 2) = make_float2(yA, yB);
  asm volatile("s_waitcnt lgkmcnt(0)" ::: "memory");
  SB0();

  // pass 2: D_i = xd_i y_i + sum_{j<i} z[i][j] y_j  (zero pads absorb masks)
  float DA = xdA * yA, DB = xdB * yB;
  float dA1 = 0.f, dB1 = 0.f;
  {
    const int r3 = lane & 3;
    const int rsi = ((lane * (lane - 1)) >> 1) + 6 * (lane >> 2) +
                    ((r3 == 2) ? 3 : (r3 == 3) ? 5 : 0);
    const int cmax = (lane + 3) >> 2;
    const __bf16* zrow = zpair + rsi * 2;
#pragma unroll 4
    for (int c = 0; c < cmax; ++c) {
      const uint4 w = *(const uint4*)(zrow + c * 8);
      const float4 u0 = *(const float4*)(yp + c * 8);
      const float4 u1 = *(const float4*)(yp + c * 8 + 4);
      DA += bf_lo(w.x) * u0.x + bf_lo(w.z) * u1.x;
      dA1 += bf_lo(w.y) * u0.z + bf_lo(w.w) * u1.z;
      DB += bf_hi(w.x) * u0.y + bf_hi(w.z) * u1.y;
      dB1 += bf_hi(w.y) * u0.w + bf_hi(w.w) * u1.w;
    }
  }
  out[(size_t)(sb + s0) * 64 + lane] = DA + dA1;
  out[(size_t)(sb + s1) * 64 + lane] = DB + dB1;
}

// ---------------- launch ----------------
extern "C" void kernel_launch(void* const* d_in, const int* in_sizes, int n_in,
                              void* d_out, int out_size, void* d_ws, size_t ws_size,
                              hipStream_t stream) {
  const float* x   = (const float*)d_in[0];
  const float* Wd1 = (const float*)d_in[1];
  const float* bd1 = (const float*)d_in[2];
  const float* Wd2 = (const float*)d_in[3];
  const float* bd2 = (const float*)d_in[4];
  const float* Wdo = (const float*)d_in[5];
  const float* bdo = (const float*)d_in[6];
  const float* Wo1 = (const float*)d_in[7];
  const float* bo1 = (const float*)d_in[8];
  const float* Wo2 = (const float*)d_in[9];
  const float* bo2 = (const float*)d_in[10];
  const float* Woo = (const float*)d_in[11];
  const float* boo = (const float*)d_in[12];
  float* out = (float*)d_out;

  char* ws = (char*)d_ws;
  // Wcat (bf16 elems): Wo1@0 | Wo2@16384 | Wd1@81920 | Wd2@98304 | Wdo@163840
  __bf16* Wcat = (__bf16*)(ws + 0);          //   360448 B
  __bf16* Woob = (__bf16*)(ws + 360448);     //  1048576 B (zero-padded rows)
  __bf16* g2   = (__bf16*)(ws + 1409024);    // 16777216 B
  float*  xdp  = (float*)(ws + 18186240);    //  8388608 B
  const size_t zoff = 26574848;
  __bf16* zq   = (__bf16*)(ws + zoff);       // z slice buffer

  // tiered z slicing: single-shot if workspace allows (full z = 1024 groups)
  const size_t zcap = (ws_size > zoff) ? (ws_size - zoff) : 0;
  int nslices = 4;
  if (zcap >= (size_t)1024 * GRP_BYTES) nslices = 1;
  else if (zcap >= (size_t)512 * GRP_BYTES) nslices = 2;
  const int QSs = B_TOT / nslices;
  const int nbm = QSs / 256;
  const int lbm = (nbm == 128) ? 7 : (nbm == 64) ? 6 : 5;

  cast_all_kernel<<<512, 256, 0, stream>>>(
      Wo1, Wcat, HDIM * NDIM,
      Wo2, Wcat + 16384, HDIM * HDIM,
      Wd1, Wcat + 81920, HDIM * NDIM,
      Wd2, Wcat + 98304, HDIM * HDIM,
      Wdo, Wcat + 163840, NDIM * HDIM,
      Woo, Woob, OFFD * HDIM,
      Woob + OFFD * HDIM, 32 * HDIM);

  hipFuncSetAttribute((const void*)off_trunk_kernel,
                      hipFuncAttributeMaxDynamicSharedMemorySize, TRK_SMEM);
  hipFuncSetAttribute((const void*)diag_trunk_kernel,
                      hipFuncAttributeMaxDynamicSharedMemorySize, TRK_SMEM);
  off_trunk_kernel<<<B_TOT / 64, 512, TRK_SMEM, stream>>>(
      x, Wcat, bo1, bo2, g2);
  diag_trunk_kernel<<<B_TOT / 64, 512, TRK_SMEM, stream>>>(
      x, Wcat + 81920, bd1, bd2, bdo, xdp);

  hipFuncSetAttribute((const void*)gemm_z_kernel,
                      hipFuncAttributeMaxDynamicSharedMemorySize, GEMM_SMEM);
  hipFuncSetAttribute((const void*)apply_kernel,
                      hipFuncAttributeMaxDynamicSharedMemorySize, APPLY_SMEM);
  for (int s = 0; s < nslices; ++s) {
    gemm_z_kernel<<<nbm * 8, 512, GEMM_SMEM, stream>>>(
        g2 + (size_t)s * QSs * HDIM, Woob, boo, zq, lbm);
    apply_kernel<<<QSs / 16, 512, APPLY_SMEM, stream>>>(zq, xdp, x, out, s * QSs);
  }
}

// Round 16
// 153.994 us; speedup vs baseline: 1.2252x; 1.0684x over previous
//
#include <hip/hip_runtime.h>
#include <math.h>

// Damping: B=32768, N=64, H=256, OFF=2016
//   diag: x -> tanh(Wd1) -> tanh(Wd2) -> Wdo   (64 per sample)
//   off : x -> tanh(Wo1) -> tanh(Wo2) -> Woo   (2016 per sample, strict lower tri)
//   out = L (L^T x0), L diag = xd, L[i][j](j<i) = z[i(i-1)/2+j]
//
// z path: gemm_z 256x256-tile LDS-staged GEMM -> HBM pair-interleaved
// padded-triangle groups (LDS-transpose epilogue, 16B stores) -> apply.

#define B_TOT 32768
#define NDIM  64
#define HDIM  256
#define OFFD  2016
#define GRP_UNITS 67584            // 16 pairs * 4224 bf16 units per 32-sample group
#define GRP_BYTES 135168

typedef __bf16 bf16x8 __attribute__((ext_vector_type(8)));
typedef float  f32x4  __attribute__((ext_vector_type(4)));

__device__ __forceinline__ float fast_tanh(float x) {
  float e = __expf(2.f * x);
  return 1.f - 2.f * __builtin_amdgcn_rcpf(e + 1.f);
}
__device__ __forceinline__ float lane_bcast(float v, int l) {
  return __uint_as_float(__builtin_amdgcn_readlane(__float_as_uint(v), l));
}
__device__ __forceinline__ float bf_lo(unsigned w) { return __uint_as_float(w << 16); }
__device__ __forceinline__ float bf_hi(unsigned w) { return __uint_as_float(w & 0xffff0000u); }
__device__ __forceinline__ unsigned bfbits(float f) {
  __bf16 h = (__bf16)f;
  return (unsigned)__builtin_bit_cast(unsigned short, h);
}
// padded-triangle row start (units of offv): row i occupies [rs(i), rs(i)+ceil4(i))
__device__ __forceinline__ int rs_of(int i) {
  const int a3 = i & 3;
  return ((i * (i - 1)) >> 1) + 6 * (i >> 2) + ((a3 == 2) ? 3 : (a3 == 3) ? 5 : 0);
}

__device__ __forceinline__ void gload_lds16(const void* g, void* l) {
  __builtin_amdgcn_global_load_lds(
      (const __attribute__((address_space(1))) unsigned*)g,
      (__attribute__((address_space(3))) unsigned*)l, 16, 0, 0);
}

#define MFMA(A, B, C) __builtin_amdgcn_mfma_f32_16x16x32_bf16((A), (B), (C), 0, 0, 0)
#define SB0() __builtin_amdgcn_sched_barrier(0)
// XOR-swizzled 16B-granule byte offset within a row (low 3 bits of granule)
#define GOFF(g, row) (((((g) & ~7) | (((g) & 7) ^ ((row) & 7)))) << 4)

// ---------------- weight cast (f32 -> bf16) + Woob pad zero-fill ----------------
__device__ __forceinline__ void cast_range(const float* __restrict__ s,
                                           __bf16* __restrict__ d, int n) {
  int i = blockIdx.x * blockDim.x + threadIdx.x;
  const int stride = gridDim.x * blockDim.x;
  for (; i < n; i += stride) d[i] = (__bf16)s[i];
}
__global__ __launch_bounds__(256) void cast_all_kernel(
    const float* s0, __bf16* d0, int n0, const float* s1, __bf16* d1, int n1,
    const float* s2, __bf16* d2, int n2, const float* s3, __bf16* d3, int n3,
    const float* s4, __bf16* d4, int n4, const float* s5, __bf16* d5, int n5,
    __bf16* d6, int n6) {
  cast_range(s0, d0, n0); cast_range(s1, d1, n1); cast_range(s2, d2, n2);
  cast_range(s3, d3, n3); cast_range(s4, d4, n4); cast_range(s5, d5, n5);
  int i = blockIdx.x * blockDim.x + threadIdx.x;
  const int stride = gridDim.x * blockDim.x;
  for (; i < n6; i += stride) d6[i] = (__bf16)0.f;
}

__device__ __forceinline__ bf16x8 cvt8(const float* __restrict__ p) {
  const float4 u = *(const float4*)p;
  const float4 v = *(const float4*)(p + 4);
  bf16x8 r;
  r[0] = (__bf16)u.x; r[1] = (__bf16)u.y; r[2] = (__bf16)u.z; r[3] = (__bf16)u.w;
  r[4] = (__bf16)v.x; r[5] = (__bf16)v.y; r[6] = (__bf16)v.z; r[7] = (__bf16)v.w;
  return r;
}

// ---------------- shared trunk machinery: 64 samples/WG, 72KB LDS, 2 WG/CU ------
#define TRK_SMEM (8192 + 32768 + 32768)

// stage one 16KB weight chunk; rows are 128B if c<2 else 512B
__device__ __forceinline__ void stage_chunk2(const char* wreg, char* wb,
                                             int c, int wave) {
  const char* base = wreg + (size_t)c * 16384;
  char* dst = wb + (c & 1) * 16384;
  const int lane = threadIdx.x & 63;
  const int s0 = wave * 64 + lane;
  const int s1 = s0 + 512;
  if (c < 2) {  // 128-byte rows (8 granules)
    const int r0 = s0 >> 3, q0 = (s0 & 7) ^ (r0 & 7);
    gload_lds16(base + r0 * 128 + (q0 << 4), dst + wave * 1024);
    const int r1 = s1 >> 3, q1 = (s1 & 7) ^ (r1 & 7);
    gload_lds16(base + r1 * 128 + (q1 << 4), dst + (wave + 8) * 1024);
  } else {      // 512-byte rows (32 granules)
    const int r0 = s0 >> 5, g0 = s0 & 31;
    const int q0 = (g0 & 24) | ((g0 & 7) ^ (r0 & 7));
    gload_lds16(base + r0 * 512 + (q0 << 4), dst + wave * 1024);
    const int r1 = s1 >> 5, g1 = s1 & 31;
    const int q1 = (g1 & 24) | ((g1 & 7) ^ (r1 & 7));
    gload_lds16(base + r1 * 512 + (q1 << 4), dst + (wave + 8) * 1024);
  }
}

// ---------------- off_trunk: x -> tanh(Wo1) -> tanh(Wo2) -> g2 ------------------
__global__ __launch_bounds__(512, 2) void off_trunk_kernel(
    const float* __restrict__ x, const __bf16* __restrict__ Wreg,
    const float* __restrict__ bo1, const float* __restrict__ bo2,
    __bf16* __restrict__ g2) {
  extern __shared__ char smem[];
  char* xa  = smem;            // 8 KB
  char* act = smem + 8192;     // 32 KB (g1)
  char* wb  = smem + 40960;    // 32 KB
  const char* Wc = (const char*)Wreg;

  const int tid = threadIdx.x;
  const int wave = tid >> 6, lane = tid & 63;
  const int lr = lane & 15, lg = lane >> 4;
  const int sb = blockIdx.x * 64;

  float bv1[2], bv2[8];
#pragma unroll
  for (int cc = 0; cc < 2; ++cc) bv1[cc] = bo1[cc * 128 + wave * 16 + lr];
#pragma unroll
  for (int cc = 0; cc < 8; ++cc) bv2[cc] = bo2[cc * 32 + (wave & 1) * 16 + lr];

  {
    const int s = tid >> 3, g = tid & 7;
    const bf16x8 v = cvt8(x + (size_t)(sb + s) * 64 + g * 8);
    *(bf16x8*)(xa + s * 128 + GOFF(g, s)) = v;
  }
  stage_chunk2(Wc, wb, 0, wave);
  __syncthreads();

#pragma unroll
  for (int cc = 0; cc < 2; ++cc) {
    stage_chunk2(Wc, wb, cc + 1, wave);
    const char* wbp = wb + (cc & 1) * 16384;
    const int brow = wave * 16 + lr;
    const bf16x8 b0 = *(const bf16x8*)(wbp + brow * 128 + GOFF(lg, brow));
    const bf16x8 b1 = *(const bf16x8*)(wbp + brow * 128 + GOFF(4 + lg, brow));
    const int ch = cc * 128 + brow;
#pragma unroll
    for (int m = 0; m < 4; ++m) {
      const int arow = m * 16 + lr;
      const bf16x8 a0 = *(const bf16x8*)(xa + arow * 128 + GOFF(lg, arow));
      const bf16x8 a1 = *(const bf16x8*)(xa + arow * 128 + GOFF(4 + lg, arow));
      f32x4 acc = {0.f, 0.f, 0.f, 0.f};
      acc = MFMA(a0, b0, acc);
      acc = MFMA(a1, b1, acc);
#pragma unroll
      for (int r = 0; r < 4; ++r) {
        const int s = m * 16 + lg * 4 + r;
        *(__bf16*)(act + s * 512 + GOFF(ch >> 3, s) + (ch & 7) * 2) =
            (__bf16)fast_tanh(acc[r] + bv1[cc]);
      }
    }
    __syncthreads();
  }

#pragma unroll
  for (int cc = 0; cc < 8; ++cc) {
    const int c = cc + 2;
    if (c + 1 < 10) stage_chunk2(Wc, wb, c + 1, wave);
    const char* wbp = wb + (c & 1) * 16384;
    const int m = wave >> 1, n = wave & 1;
    const int ch = cc * 32 + n * 16 + lr;
    const int brow = n * 16 + lr;
    const int arow = m * 16 + lr;
    f32x4 acc = {0.f, 0.f, 0.f, 0.f};
#pragma unroll
    for (int ks = 0; ks < 8; ++ks) {
      const int g = ks * 4 + lg;
      const bf16x8 a = *(const bf16x8*)(act + arow * 512 + GOFF(g, arow));
      const bf16x8 b = *(const bf16x8*)(wbp + brow * 512 + GOFF(g, brow));
      acc = MFMA(a, b, acc);
    }
#pragma unroll
    for (int r = 0; r < 4; ++r) {
      const int s = m * 16 + lg * 4 + r;
      g2[(size_t)(sb + s) * 256 + ch] = (__bf16)fast_tanh(acc[r] + bv2[cc]);
    }
    if (cc < 7) __syncthreads();
  }
}

// ---------------- diag_trunk: x -> tanh(Wd1) -> tanh(Wd2) -> Wdo -> xd ----------
__global__ __launch_bounds__(512, 2) void diag_trunk_kernel(
    const float* __restrict__ x, const __bf16* __restrict__ Wreg,
    const float* __restrict__ bd1, const float* __restrict__ bd2,
    const float* __restrict__ bdo, float* __restrict__ xd) {
  extern __shared__ char smem[];
  char* xa  = smem;            // 8 KB
  char* act = smem + 8192;     // 32 KB (h1, then h2)
  char* wb  = smem + 40960;    // 32 KB
  const char* Wc = (const char*)Wreg;

  const int tid = threadIdx.x;
  const int wave = tid >> 6, lane = tid & 63;
  const int lr = lane & 15, lg = lane >> 4;
  const int sb = blockIdx.x * 64;

  float bv1[2], bv2[8], bv3[2];
#pragma unroll
  for (int cc = 0; cc < 2; ++cc) bv1[cc] = bd1[cc * 128 + wave * 16 + lr];
#pragma unroll
  for (int cc = 0; cc < 8; ++cc) bv2[cc] = bd2[cc * 32 + (wave & 1) * 16 + lr];
#pragma unroll
  for (int cc = 0; cc < 2; ++cc) bv3[cc] = bdo[cc * 32 + (wave & 1) * 16 + lr];

  {
    const int s = tid >> 3, g = tid & 7;
    const bf16x8 v = cvt8(x + (size_t)(sb + s) * 64 + g * 8);
    *(bf16x8*)(xa + s * 128 + GOFF(g, s)) = v;
  }
  stage_chunk2(Wc, wb, 0, wave);
  __syncthreads();

#pragma unroll
  for (int cc = 0; cc < 2; ++cc) {
    stage_chunk2(Wc, wb, cc + 1, wave);
    const char* wbp = wb + (cc & 1) * 16384;
    const int brow = wave * 16 + lr;
    const bf16x8 b0 = *(const bf16x8*)(wbp + brow * 128 + GOFF(lg, brow));
    const bf16x8 b1 = *(const bf16x8*)(wbp + brow * 128 + GOFF(4 + lg, brow));
    const int ch = cc * 128 + brow;
#pragma unroll
    for (int m = 0; m < 4; ++m) {
      const int arow = m * 16 + lr;
      const bf16x8 a0 = *(const bf16x8*)(xa + arow * 128 + GOFF(lg, arow));
      const bf16x8 a1 = *(const bf16x8*)(xa + arow * 128 + GOFF(4 + lg, arow));
      f32x4 acc = {0.f, 0.f, 0.f, 0.f};
      acc = MFMA(a0, b0, acc);
      acc = MFMA(a1, b1, acc);
#pragma unroll
      for (int r = 0; r < 4; ++r) {
        const int s = m * 16 + lg * 4 + r;
        *(__bf16*)(act + s * 512 + GOFF(ch >> 3, s) + (ch & 7) * 2) =
            (__bf16)fast_tanh(acc[r] + bv1[cc]);
      }
    }
    __syncthreads();
  }

  f32x4 h2v[8];
#pragma unroll
  for (int cc = 0; cc < 8; ++cc) {
    const int c = cc + 2;
    if (c + 1 < 11) stage_chunk2(Wc, wb, c + 1, wave);
    const char* wbp = wb + (c & 1) * 16384;
    const int m = wave >> 1, n = wave & 1;
    const int brow = n * 16 + lr;
    const int arow = m * 16 + lr;
    f32x4 acc = {0.f, 0.f, 0.f, 0.f};
#pragma unroll
    for (int ks = 0; ks < 8; ++ks) {
      const int g = ks * 4 + lg;
      const bf16x8 a = *(const bf16x8*)(act + arow * 512 + GOFF(g, arow));
      const bf16x8 b = *(const bf16x8*)(wbp + brow * 512 + GOFF(g, brow));
      acc = MFMA(a, b, acc);
    }
#pragma unroll
    for (int r = 0; r < 4; ++r) h2v[cc][r] = fast_tanh(acc[r] + bv2[cc]);
    __syncthreads();
  }

  {
    const int m = wave >> 1, n = wave & 1;
#pragma unroll
    for (int cc = 0; cc < 8; ++cc) {
      const int ch = cc * 32 + n * 16 + lr;
#pragma unroll
      for (int r = 0; r < 4; ++r) {
        const int s = m * 16 + lg * 4 + r;
        *(__bf16*)(act + s * 512 + GOFF(ch >> 3, s) + (ch & 7) * 2) =
            (__bf16)h2v[cc][r];
      }
    }
  }
  stage_chunk2(Wc, wb, 11, wave);
  __syncthreads();

#pragma unroll
  for (int cc = 0; cc < 2; ++cc) {
    const char* wbp = wb + ((10 + cc) & 1) * 16384;
    const int m = wave >> 1, n = wave & 1;
    const int ch = cc * 32 + n * 16 + lr;
    const int brow = n * 16 + lr;
    const int arow = m * 16 + lr;
    f32x4 acc = {0.f, 0.f, 0.f, 0.f};
#pragma unroll
    for (int ks = 0; ks < 8; ++ks) {
      const int g = ks * 4 + lg;
      const bf16x8 a = *(const bf16x8*)(act + arow * 512 + GOFF(g, arow));
      const bf16x8 b = *(const bf16x8*)(wbp + brow * 512 + GOFF(g, brow));
      acc = MFMA(a, b, acc);
    }
#pragma unroll
    for (int r = 0; r < 4; ++r) {
      const int s = m * 16 + lg * 4 + r;
      xd[(size_t)(sb + s) * 64 + ch] = acc[r] + bv3[cc];
    }
  }
}

// ---------------- gemm_z: 256x256 tiles, LDS-transpose epilogue ----------------
// LDS: 4x32KB staging (reused as 128KB C-transpose tile T after the K loop)
// + 1KB granule list. T layout: [ncol 256][row-granule 64 u64], granule
// XOR-swizzled by (ncol&7). Dest granule = 4 consecutive offv x pair (16B).
#define TILE_BYTES 32768
#define LIST_OFF   131072
#define LIST_CAP   160
#define GEMM_SMEM  (131072 + 1024)

__global__ __launch_bounds__(512, 1) void gemm_z_kernel(
    const __bf16* __restrict__ g2q, const __bf16* __restrict__ Woob,
    const float* __restrict__ boo, __bf16* __restrict__ zq, int bmper) {
  extern __shared__ char gsm[];
  const int tid = threadIdx.x;
  const int wave = tid >> 6, lane = tid & 63;
  const int lr = lane & 15, lg = lane >> 4;
  // XCD owns a contiguous bm range: g2 slice + full Woo stay L2-resident
  const int bm = (blockIdx.x & 7) * bmper + (blockIdx.x >> 6);
  const int bn = (blockIdx.x >> 3) & 7;
  const int wr = wave >> 2, wc = wave & 3;
  const int srl = lane >> 3;
  const int sch = lane & 7;

#define STAGE(BUF, KT)                                                          \
  {                                                                             \
    _Pragma("unroll")                                                           \
    for (int j = 0; j < 4; ++j) {                                               \
      const int row = wave * 32 + j * 8 + srl;                                  \
      const int ka = (KT) * 64 + ((sch ^ (row & 7)) << 3);                      \
      gload_lds16(g2q + (size_t)(bm * 256 + row) * 256 + ka,                    \
                  gsm + (BUF) * TILE_BYTES + wave * 4096 + j * 1024);           \
      gload_lds16(Woob + (size_t)(bn * 256 + row) * 256 + ka,                   \
                  gsm + 65536 + (BUF) * TILE_BYTES + wave * 4096 + j * 1024);   \
    }                                                                           \
  }

  int* lcnt = (int*)(gsm + LIST_OFF);
  unsigned* llist = (unsigned*)(gsm + LIST_OFF + 4);
  const int base = bn * 256;

  // bias per fc (prologue; hides under staging)
  float bvf[4];
#pragma unroll
  for (int fc = 0; fc < 4; ++fc) {
    const int col = base + wc * 64 + fc * 16 + lr;
    bvf[fc] = (col < OFFD) ? boo[col] : 0.f;
  }

  f32x4 acc[8][4];
#pragma unroll
  for (int i = 0; i < 8; ++i)
#pragma unroll
    for (int j = 0; j < 4; ++j) acc[i][j] = (f32x4){0.f, 0.f, 0.f, 0.f};

  STAGE(0, 0)
  if (tid == 0) *lcnt = 0;
  __syncthreads();

  // build compacted dest-granule list for this bn window (once per WG)
  for (int gi = tid; gi < 528; gi += 512) {
    const int off0 = gi * 4;
    int i = (int)((1.f + sqrtf((float)(8 * off0 + 1))) * 0.5f);
    if (i > 63) i = 63;
    if (i < 1) i = 1;
    while (i > 1 && rs_of(i) > off0) --i;
    while (i < 63 && rs_of(i + 1) <= off0) ++i;
    const int j0 = off0 - rs_of(i);
    int nv = i - j0;
    if (nv > 4) nv = 4;
    const int c0 = ((i * (i - 1)) >> 1) + j0;
    const int last = c0 + nv - 1;
    if (last >= base && c0 <= base + 255) {
      const int idx = atomicAdd(lcnt, 1);
      if (idx < LIST_CAP)
        llist[idx] = ((unsigned)gi << 16) | ((unsigned)i << 9) |
                     ((unsigned)j0 << 3) | (unsigned)nv;
    }
  }
  __syncthreads();

#pragma unroll
  for (int kt = 0; kt < 4; ++kt) {
    if (kt < 3) STAGE((kt + 1) & 1, kt + 1)
    const __bf16* Ab = (const __bf16*)(gsm + (kt & 1) * TILE_BYTES);
    const __bf16* Bb = (const __bf16*)(gsm + 65536 + (kt & 1) * TILE_BYTES);
#pragma unroll
    for (int ks = 0; ks < 2; ++ks) {
      const int cc = ((ks * 4 + lg) ^ (lr & 7)) << 3;
      bf16x8 af[8];
#pragma unroll
      for (int fr = 0; fr < 8; ++fr)
        af[fr] = *(const bf16x8*)(Ab + (wr * 128 + fr * 16 + lr) * 64 + cc);
      bf16x8 bfr[4];
#pragma unroll
      for (int fc = 0; fc < 4; ++fc)
        bfr[fc] = *(const bf16x8*)(Bb + (wc * 64 + fc * 16 + lr) * 64 + cc);
#pragma unroll
      for (int fr = 0; fr < 8; ++fr)
#pragma unroll
        for (int fc = 0; fc < 4; ++fc)
          acc[fr][fc] = MFMA(af[fr], bfr[fc], acc[fr][fc]);
    }
    __syncthreads();   // last iteration: certifies staging reads before T reuse
  }

  // ---- epilogue v2: dump C-tile to LDS T, then coalesced 16B stores ----
  {
    unsigned long long* Tq = (unsigned long long*)gsm;
#pragma unroll
    for (int fr = 0; fr < 8; ++fr) {
      const int rgrp = wr * 32 + fr * 4 + lg;   // 4-row granule index
#pragma unroll
      for (int fc = 0; fc < 4; ++fc) {
        const int ncol = wc * 64 + fc * 16 + lr;
        const unsigned long long v =
            (unsigned long long)bfbits(acc[fr][fc][0] + bvf[fc]) |
            ((unsigned long long)bfbits(acc[fr][fc][1] + bvf[fc]) << 16) |
            ((unsigned long long)bfbits(acc[fr][fc][2] + bvf[fc]) << 32) |
            ((unsigned long long)bfbits(acc[fr][fc][3] + bvf[fc]) << 48);
        Tq[ncol * 64 + (rgrp ^ (ncol & 7))] = v;
      }
    }
  }
  __syncthreads();

  {
    const unsigned* Tw = (const unsigned*)gsm;
    int nl = *lcnt;
    if (nl > LIST_CAP) nl = LIST_CAP;
    const int p = tid >> 2;                  // local pair 0..127
    const int grp = bm * 8 + (p >> 4);
    __bf16* zdst = zq + (size_t)grp * GRP_UNITS + (p & 15) * 4224;
    for (int li = (tid & 3); li < nl; li += 4) {
      const unsigned e = llist[li];
      const int gi = e >> 16;
      const int i = (e >> 9) & 63;
      const int j0 = (e >> 3) & 63;
      const int nv = e & 7;
      const int c0 = ((i * (i - 1)) >> 1) + j0;
      const int lc0 = c0 - base;
      unsigned u[4];
#pragma unroll
      for (int d = 0; d < 4; ++d) {
        const int lc = lc0 + d;
        const bool valid = (d < nv) && (lc >= 0) && (lc <= 255);
        u[d] = valid
                   ? Tw[lc * 128 + (((p >> 1) ^ (lc & 7)) << 1) + (p & 1)]
                   : 0u;
      }
      const bool full = (lc0 >= 0) && (lc0 + nv - 1 <= 255);
      if (full) {
        uint4 w;
        w.x = u[0]; w.y = u[1]; w.z = u[2]; w.w = u[3];
        *(uint4*)(zdst + (size_t)gi * 8) = w;
      } else {
        const bool ownpad = (lc0 + nv - 1 >= 0) && (lc0 + nv - 1 <= 255);
#pragma unroll
        for (int d = 0; d < 4; ++d) {
          const int lc = lc0 + d;
          const bool own =
              (d < nv) ? ((lc >= 0) && (lc <= 255)) : ownpad;
          if (own) *(unsigned*)(zdst + (size_t)gi * 8 + d * 2) = u[d];
        }
      }
    }
  }
}

// ---------------- apply: 512 thr, 16 samples (half group) -> 2 WG/CU ------------
#define APPLY_SMEM (8 * 8448 + 4096)
__global__ __launch_bounds__(512, 2) void apply_kernel(
    const __bf16* __restrict__ zq, const float* __restrict__ xd,
    const float* __restrict__ x0, float* __restrict__ out, int s0base) {
  extern __shared__ char smem[];
  __bf16* ztb = (__bf16*)smem;                 // 8 pairs x 4224 units
  float* ys2 = (float*)(smem + 8 * 8448);      // [8][128]

  const int tid = threadIdx.x;
  const int wave = tid >> 6, lane = tid & 63;
  const int blk = blockIdx.x;
  const int sb = s0base + blk * 16;
  const int s0 = wave * 2, s1 = s0 + 1;

  const float x0vA = x0[(size_t)(sb + s0) * 64 + lane];
  const float x0vB = x0[(size_t)(sb + s1) * 64 + lane];
  const float xdA = xd[(size_t)(sb + s0) * 64 + lane];
  const float xdB = xd[(size_t)(sb + s1) * 64 + lane];

  {
    const char* src = (const char*)zq + (size_t)(blk >> 1) * GRP_BYTES +
                      ((blk & 1) * 8 + wave) * 8448;
    char* dst = smem + wave * 8448;
#pragma unroll
    for (int j = 0; j < 8; ++j)
      gload_lds16(src + j * 1024 + lane * 16, dst + j * 1024);
    if (lane < 16) gload_lds16(src + 8192 + lane * 16, dst + 8192);
  }
  asm volatile("s_waitcnt vmcnt(0)" ::: "memory");
  SB0();

  const __bf16* zpair = ztb + wave * 4224;

  // pass 1: y_j = xd_j x0_j + sum_{k>j} z[k][j] x0_k
  float yA = xdA * x0vA, yB = xdB * x0vB;
  int rs = 0;
#pragma unroll
  for (int k = 1; k < 64; ++k) {
    const unsigned w = *(const unsigned*)(zpair + (rs + lane) * 2);
    const float xkA = lane_bcast(x0vA, k);
    const float xkB = lane_bcast(x0vB, k);
    const bool mvalid = lane < k;
    yA += mvalid ? bf_lo(w) * xkA : 0.f;
    yB += mvalid ? bf_hi(w) * xkB : 0.f;
    rs += (k + 3) & ~3;
  }

  float* yp = ys2 + wave * 128;
  *(float2*)(yp + lane * 2) = make_float2(yA, yB);
  asm volatile("s_waitcnt lgkmcnt(0)" ::: "memory");
  SB0();

  // pass 2: D_i = xd_i y_i + sum_{j<i} z[i][j] y_j  (zero pads absorb masks)
  float DA = xdA * yA, DB = xdB * yB;
  float dA1 = 0.f, dB1 = 0.f;
  {
    const int r3 = lane & 3;
    const int rsi = ((lane * (lane - 1)) >> 1) + 6 * (lane >> 2) +
                    ((r3 == 2) ? 3 : (r3 == 3) ? 5 : 0);
    const int cmax = (lane + 3) >> 2;
    const __bf16* zrow = zpair + rsi * 2;
#pragma unroll 4
    for (int c = 0; c < cmax; ++c) {
      const uint4 w = *(const uint4*)(zrow + c * 8);
      const float4 u0 = *(const float4*)(yp + c * 8);
      const float4 u1 = *(const float4*)(yp + c * 8 + 4);
      DA += bf_lo(w.x) * u0.x + bf_lo(w.z) * u1.x;
      dA1 += bf_lo(w.y) * u0.z + bf_lo(w.w) * u1.z;
      DB += bf_hi(w.x) * u0.y + bf_hi(w.z) * u1.y;
      dB1 += bf_hi(w.y) * u0.w + bf_hi(w.w) * u1.w;
    }
  }
  out[(size_t)(sb + s0) * 64 + lane] = DA + dA1;
  out[(size_t)(sb + s1) * 64 + lane] = DB + dB1;
}

// ---------------- launch ----------------
extern "C" void kernel_launch(void* const* d_in, const int* in_sizes, int n_in,
                              void* d_out, int out_size, void* d_ws, size_t ws_size,
                              hipStream_t stream) {
  const float* x   = (const float*)d_in[0];
  const float* Wd1 = (const float*)d_in[1];
  const float* bd1 = (const float*)d_in[2];
  const float* Wd2 = (const float*)d_in[3];
  const float* bd2 = (const float*)d_in[4];
  const float* Wdo = (const float*)d_in[5];
  const float* bdo = (const float*)d_in[6];
  const float* Wo1 = (const float*)d_in[7];
  const float* bo1 = (const float*)d_in[8];
  const float* Wo2 = (const float*)d_in[9];
  const float* bo2 = (const float*)d_in[10];
  const float* Woo = (const float*)d_in[11];
  const float* boo = (const float*)d_in[12];
  float* out = (float*)d_out;

  char* ws = (char*)d_ws;
  // Wcat (bf16 elems): Wo1@0 | Wo2@16384 | Wd1@81920 | Wd2@98304 | Wdo@163840
  __bf16* Wcat = (__bf16*)(ws + 0);          //   360448 B
  __bf16* Woob = (__bf16*)(ws + 360448);     //  1048576 B (zero-padded rows)
  __bf16* g2   = (__bf16*)(ws + 1409024);    // 16777216 B
  float*  xdp  = (float*)(ws + 18186240);    //  8388608 B
  const size_t zoff = 26574848;
  __bf16* zq   = (__bf16*)(ws + zoff);       // z slice buffer

  const size_t zcap = (ws_size > zoff) ? (ws_size - zoff) : 0;
  int nslices = 4;
  if (zcap >= (size_t)1024 * GRP_BYTES) nslices = 1;
  else if (zcap >= (size_t)512 * GRP_BYTES) nslices = 2;
  const int QSs = B_TOT / nslices;
  const int nbm = QSs / 256;
  const int bmper = nbm >> 3;

  cast_all_kernel<<<512, 256, 0, stream>>>(
      Wo1, Wcat, HDIM * NDIM,
      Wo2, Wcat + 16384, HDIM * HDIM,
      Wd1, Wcat + 81920, HDIM * NDIM,
      Wd2, Wcat + 98304, HDIM * HDIM,
      Wdo, Wcat + 163840, NDIM * HDIM,
      Woo, Woob, OFFD * HDIM,
      Woob + OFFD * HDIM, 32 * HDIM);

  hipFuncSetAttribute((const void*)off_trunk_kernel,
                      hipFuncAttributeMaxDynamicSharedMemorySize, TRK_SMEM);
  hipFuncSetAttribute((const void*)diag_trunk_kernel,
                      hipFuncAttributeMaxDynamicSharedMemorySize, TRK_SMEM);
  off_trunk_kernel<<<B_TOT / 64, 512, TRK_SMEM, stream>>>(
      x, Wcat, bo1, bo2, g2);
  diag_trunk_kernel<<<B_TOT / 64, 512, TRK_SMEM, stream>>>(
      x, Wcat + 81920, bd1, bd2, bdo, xdp);

  hipFuncSetAttribute((const void*)gemm_z_kernel,
                      hipFuncAttributeMaxDynamicSharedMemorySize, GEMM_SMEM);
  hipFuncSetAttribute((const void*)apply_kernel,
                      hipFuncAttributeMaxDynamicSharedMemorySize, APPLY_SMEM);
  for (int s = 0; s < nslices; ++s) {
    gemm_z_kernel<<<nbm * 8, 512, GEMM_SMEM, stream>>>(
        g2 + (size_t)s * QSs * HDIM, Woob, boo, zq, bmper);
    apply_kernel<<<QSs / 16, 512, APPLY_SMEM, stream>>>(zq, xdp, x, out, s * QSs);
  }
}